// Round 2
// baseline (267.732 us; speedup 1.0000x reference)
//
#include <hip/hip_runtime.h>
#include <hip/hip_bf16.h>
#include <cstdint>
#include <cstddef>

// Problem constants (reference: B=8, S=4096, N_STATE=1024, N_HEAD=16)
#define B_SZ    8
#define S_LEN   4096
#define NHEAD   16
#define HDIM    64
#define NROT    32
#define NFREQ   32                      // HDIM/2
#define NROWS   (B_SZ * S_LEN * NHEAD)  // 524288 rows of 64 floats
#define NG64    (NROWS / 64)            // 8192 groups of 64 rows per wave

typedef __attribute__((address_space(1))) unsigned int gu32;
typedef __attribute__((address_space(3))) unsigned int lu32;

// ---------------------------------------------------------------------------
// Setup: blocks 0..511 fill the RoPE sin/cos tables (4096 x 32 each);
// block 512 composes M = G0*G1*...*G31 * R, stored ROW-major: M[k*64+c].
// ---------------------------------------------------------------------------
__global__ void setup_kernel(const float* __restrict__ thetas,
                             const float* __restrict__ theta_scale,
                             const float* __restrict__ r_matrix,
                             const int*   __restrict__ r_pairs,
                             const float* __restrict__ inv_freq,
                             float* __restrict__ M,
                             float* __restrict__ cosT,
                             float* __restrict__ sinT) {
  if (blockIdx.x < 512) {
    int idx = blockIdx.x * 256 + threadIdx.x;   // 0 .. 131071 = s*32 + f
    int s = idx >> 5;
    int f = idx & 31;
    float ang = (float)s * inv_freq[f];
    cosT[idx] = cosf(ang);
    sinT[idx] = sinf(ang);
    return;
  }
  __shared__ float C[64 * 65];                  // pad 65: no bank conflicts
  int tid = threadIdx.x;
  if (tid < 64) {
    for (int c = 0; c < 64; ++c) C[tid * 65 + c] = (tid == c) ? 1.0f : 0.0f;
    float sc = theta_scale[0];
    for (int q = 0; q < NROT; ++q) {
      float th = thetas[q] * sc;
      float cs = cosf(th), sn = sinf(th);
      int i = r_pairs[2 * q], j = r_pairs[2 * q + 1];
      float xi = C[tid * 65 + i];
      float xj = C[tid * 65 + j];
      C[tid * 65 + i] =  xi * cs + xj * sn;
      C[tid * 65 + j] = -xi * sn + xj * cs;
    }
  }
  __syncthreads();
  // M[t][c] = sum_k C[t][k] * R[k][c]   (row-major)
  for (int o = tid; o < 64 * 64; o += 256) {
    int t = o >> 6, c = o & 63;
    float a = 0.0f;
    for (int k = 0; k < 64; ++k) a = fmaf(C[t * 65 + k], r_matrix[k * 64 + c], a);
    M[t * 64 + c] = a;
  }
}

// ---------------------------------------------------------------------------
// Main: one wave per 64-row group; lane r owns row r. x staged to LDS in 4
// K-subtiles [64 rows][64B] (double-buffered, counted vmcnt, wave-private),
// XOR-swizzled via pre-swizzled global source (granule ^= (row>>1)&3) so the
// per-lane ds_read_b128 row reads are bank-conflict-free. M[k][c] is
// wave-uniform -> s_load (scalar pipe) feeding v_fma with SGPR operand.
// RoPE pairs are in-lane; stores are 16B chunks covering full 256B rows.
// ---------------------------------------------------------------------------
__global__ __launch_bounds__(256)
void rotary_main(const float* __restrict__ x,
                 const float* __restrict__ M,
                 const float* __restrict__ cosT,
                 const float* __restrict__ sinT,
                 float* __restrict__ out) {
  __shared__ float sx[4][2][1024];              // 4 waves x 2 subtile bufs x 4KB
  const int tid  = threadIdx.x;
  const int lane = tid & 63;
  const int wid  = tid >> 6;
  const int l4   = lane >> 2;                   // 0..15: staging row-in-quarter
  const int lg   = lane & 3;                    // 0..3 : staging granule slot
  const int gswS = lg ^ ((l4 >> 1) & 3);        // source granule (storage swizzle)

  const int g = blockIdx.x * 4 + wid;           // group id, 0..8191 (exact)
  const float* xg = x + (size_t)g * 4096;
  float* og = out + (size_t)g * 4096 + (size_t)lane * 64;

  // stage K-subtile kb (cols 16kb..16kb+15 of all 64 rows) into buffer b.
  // LDS dest is linear (lane*16); source granule is pre-swizzled (m173).
  auto stage = [&](int kb, int b) {
    float* dst = &sx[wid][b][0];
    #pragma unroll
    for (int q = 0; q < 4; ++q) {
      const int row = q * 16 + l4;
      const float* src = xg + row * 64 + kb * 16 + gswS * 4;
      __builtin_amdgcn_global_load_lds((gu32*)(const void*)src,
                                       (lu32*)(void*)(dst + q * 256), 16, 0, 0);
    }
  };

  float acc[64];
  #pragma unroll
  for (int c = 0; c < 64; ++c) acc[c] = 0.0f;

  stage(0, 0);
  stage(1, 1);

  const int rsw = (lane >> 1) & 3;              // read-side swizzle key

  for (int kb = 0; kb < 4; ++kb) {
    if (kb < 3) { asm volatile("s_waitcnt vmcnt(4)" ::: "memory"); }
    else        { asm volatile("s_waitcnt vmcnt(0)" ::: "memory"); }
    __builtin_amdgcn_sched_barrier(0);

    const float* buf = &sx[wid][kb & 1][0];
    float4 xv[4];
    #pragma unroll
    for (int u = 0; u < 4; ++u) {
      const int p = u ^ rsw;                    // swizzled granule position
      xv[u] = *reinterpret_cast<const float4*>(buf + lane * 16 + p * 4);
    }

    const float* Mk = M + kb * 16 * 64;
    #pragma unroll
    for (int u = 0; u < 4; ++u) {
      #pragma unroll
      for (int ku = 0; ku < 4; ++ku) {
        const float xk = (&xv[u].x)[ku];
        const float* Mr = Mk + (u * 4 + ku) * 64;   // wave-uniform -> s_load
        #pragma unroll
        for (int c = 0; c < 64; ++c)
          acc[c] = fmaf(xk, Mr[c], acc[c]);
      }
    }

    if (kb < 2) stage(kb + 2, kb & 1);          // prefetch into freed buffer
  }

  // Epilogue: RoPE in-lane. s for this lane's row; cos/sin from tables.
  const int s = ((g * 64 + lane) >> 4) & (S_LEN - 1);
  const float* ct = cosT + s * NFREQ;
  const float* st = sinT + s * NFREQ;
  #pragma unroll
  for (int db = 0; db < 4; ++db) {
    const int d0 = db * 8;
    float4 ca = *reinterpret_cast<const float4*>(ct + d0);
    float4 cb = *reinterpret_cast<const float4*>(ct + d0 + 4);
    float4 sa = *reinterpret_cast<const float4*>(st + d0);
    float4 sb = *reinterpret_cast<const float4*>(st + d0 + 4);
    float co[8] = {ca.x, ca.y, ca.z, ca.w, cb.x, cb.y, cb.z, cb.w};
    float si[8] = {sa.x, sa.y, sa.z, sa.w, sb.x, sb.y, sb.z, sb.w};
    float lo[8], hi[8];
    #pragma unroll
    for (int j = 0; j < 8; ++j) {
      float x1 = acc[2 * (d0 + j)];
      float x2 = acc[2 * (d0 + j) + 1];
      lo[j] = fmaf(x1, co[j], -(x2 * si[j]));   // out[d]    = x1*c - x2*s
      hi[j] = fmaf(x1, si[j],   x2 * co[j]);    // out[32+d] = x1*s + x2*c
    }
    *reinterpret_cast<float4*>(og + d0)      = make_float4(lo[0], lo[1], lo[2], lo[3]);
    *reinterpret_cast<float4*>(og + d0 + 4)  = make_float4(lo[4], lo[5], lo[6], lo[7]);
    *reinterpret_cast<float4*>(og + 32 + d0)     = make_float4(hi[0], hi[1], hi[2], hi[3]);
    *reinterpret_cast<float4*>(og + 32 + d0 + 4) = make_float4(hi[4], hi[5], hi[6], hi[7]);
  }
}

extern "C" void kernel_launch(void* const* d_in, const int* in_sizes, int n_in,
                              void* d_out, int out_size, void* d_ws, size_t ws_size,
                              hipStream_t stream) {
  const float* x           = (const float*)d_in[0];
  const float* thetas      = (const float*)d_in[1];
  const float* theta_scale = (const float*)d_in[2];
  const float* r_matrix    = (const float*)d_in[3];
  const float* inv_freq    = (const float*)d_in[4];
  const int*   r_pairs     = (const int*)d_in[5];

  float* M    = (float*)d_ws;                   // 4096 floats (16KB)
  float* cosT = M + 4096;                       // 131072 floats (512KB)
  float* sinT = cosT + S_LEN * NFREQ;           // 131072 floats (512KB)
  float* outp = (float*)d_out;

  setup_kernel<<<513, 256, 0, stream>>>(thetas, theta_scale, r_matrix, r_pairs,
                                        inv_freq, M, cosT, sinT);
  rotary_main<<<NG64 / 4, 256, 0, stream>>>(x, M, cosT, sinT, outp);
}

// Round 3
// 106.103 us; speedup vs baseline: 2.5233x; 2.5233x over previous
//
#include <hip/hip_runtime.h>
#include <cstdint>
#include <cstddef>

// Problem constants (reference: B=8, S=4096, N_STATE=1024, N_HEAD=16)
#define S_LEN   4096
#define NROT    32
#define NGRP    8192    // groups of 64 rows (64x64 fp32 tile each)
#define NWAVE   4096    // 2 groups per wave

typedef __attribute__((ext_vector_type(8))) short  short8x;  // 8 bf16 (4 VGPR)
typedef __attribute__((ext_vector_type(4))) float  floatx4;  // 4 f32

__device__ __host__ inline unsigned short f2bf(float f) {
  union { float f; unsigned u; } c; c.f = f;
  unsigned u = c.u;
  return (unsigned short)((u + 0x7fffu + ((u >> 16) & 1u)) >> 16);
}
__device__ inline float bf2f(unsigned short h) {
  union { unsigned u; float f; } c; c.u = ((unsigned)h) << 16;
  return c.f;
}

// ---------------------------------------------------------------------------
// Setup: blocks 0..511 fill cos/sin tables (4096 x 32 each).
// Block 512: compose M = G0..G31 * R, split into bf16 hi/lo, and emit the
// 16 B-operand MFMA fragments (nt x ks x {hi,lo}) in lane-fragment order:
//   Bfrag[f*64 + lane] = 8 bf16: B[k = ks*32 + (lane>>4)*8 + j][col = nt*16 + (lane&15)]
// ---------------------------------------------------------------------------
__global__ void setup_kernel(const float* __restrict__ thetas,
                             const float* __restrict__ theta_scale,
                             const float* __restrict__ r_matrix,
                             const int*   __restrict__ r_pairs,
                             const float* __restrict__ inv_freq,
                             uint4* __restrict__ Bfrag,
                             float* __restrict__ cosT,
                             float* __restrict__ sinT) {
  if (blockIdx.x < 512) {
    int idx = blockIdx.x * 256 + threadIdx.x;   // 0..131071 = s*32 + f
    int s = idx >> 5;
    int f = idx & 31;
    float ang = (float)s * inv_freq[f];
    cosT[idx] = cosf(ang);
    sinT[idx] = sinf(ang);
    return;
  }
  __shared__ float C[64 * 65];                  // rotations applied to identity
  __shared__ float Mm[64 * 64];                 // final M = C * R (row-major)
  int tid = threadIdx.x;
  if (tid < 64) {
    for (int c = 0; c < 64; ++c) C[tid * 65 + c] = (tid == c) ? 1.0f : 0.0f;
    float sc = theta_scale[0];
    for (int q = 0; q < NROT; ++q) {
      float th = thetas[q] * sc;
      float cs = cosf(th), sn = sinf(th);
      int i = r_pairs[2 * q], j = r_pairs[2 * q + 1];
      float xi = C[tid * 65 + i];
      float xj = C[tid * 65 + j];
      C[tid * 65 + i] =  xi * cs + xj * sn;
      C[tid * 65 + j] = -xi * sn + xj * cs;
    }
  }
  __syncthreads();
  for (int o = tid; o < 64 * 64; o += 256) {
    int t = o >> 6, c = o & 63;
    float a = 0.0f;
    for (int k = 0; k < 64; ++k) a = fmaf(C[t * 65 + k], r_matrix[k * 64 + c], a);
    Mm[o] = a;
  }
  __syncthreads();
  // emit 16 fragments x 64 lanes
  for (int e = tid; e < 16 * 64; e += 256) {
    int f = e >> 6, l = e & 63;
    int hl = f & 1, ks = (f >> 1) & 1, nt = f >> 2;
    int col = nt * 16 + (l & 15);
    unsigned short w[8];
    for (int j = 0; j < 8; ++j) {
      int k = ks * 32 + (l >> 4) * 8 + j;
      float m = Mm[k * 64 + col];
      unsigned short h = f2bf(m);
      if (hl == 0) w[j] = h;
      else         w[j] = f2bf(m - bf2f(h));
    }
    uint4 pk;
    pk.x = (unsigned)w[0] | ((unsigned)w[1] << 16);
    pk.y = (unsigned)w[2] | ((unsigned)w[3] << 16);
    pk.z = (unsigned)w[4] | ((unsigned)w[5] << 16);
    pk.w = (unsigned)w[6] | ((unsigned)w[7] << 16);
    Bfrag[e] = pk;
  }
}

// ---------------------------------------------------------------------------
// Main: one wave per 64x64 group (2 groups/wave). A-fragments read straight
// from global (8 contiguous fp32/lane), converted to bf16 hi/lo in regs.
// y = A*M via 6 chained mfma_f32_16x16x32_bf16 per 16x16 tile (3 split terms
// x 2 k-steps). Epilogue: s = g*4+mt is wave-uniform; RoPE pair via
// shfl_xor(1); 32B-sector-aligned dword stores. No LDS, no barriers.
// ---------------------------------------------------------------------------
__global__ __launch_bounds__(256)
void rotary_main(const float* __restrict__ x,
                 const uint4* __restrict__ Bfrag,
                 const float* __restrict__ cosT,
                 const float* __restrict__ sinT,
                 float* __restrict__ out) {
  const int tid  = threadIdx.x;
  const int lane = tid & 63;
  const int wid  = tid >> 6;
  const int w    = blockIdx.x * 4 + wid;        // wave id 0..4095

  // B fragments: 16 x 16B per lane (256B), persistent
  const short8x* Bp = (const short8x*)Bfrag;
  short8x Bf[16];
  #pragma unroll
  for (int f = 0; f < 16; ++f) Bf[f] = Bp[f * 64 + lane];

  const int lr = lane & 15;                     // row-within-tile (A) / col (C)
  const int lk = lane >> 4;                     // k-block (A) / row-block (C)
  const int dq = lr >> 1;                       // pair index within tile cols

  for (int gi = 0; gi < 2; ++gi) {
    const int g = w * 2 + gi;                   // group 0..8191
    const float* xg = x + (size_t)g * 4096;
    float* og = out + (size_t)g * 4096;

    for (int mt = 0; mt < 4; ++mt) {
      // A: 8 contiguous fp32 per lane per k-step
      const float* xr = xg + (size_t)(mt * 16 + lr) * 64 + lk * 8;
      floatx4 a00 = *(const floatx4*)(xr);
      floatx4 a01 = *(const floatx4*)(xr + 4);
      floatx4 a10 = *(const floatx4*)(xr + 32);
      floatx4 a11 = *(const floatx4*)(xr + 36);

      short8x Ah0, Al0, Ah1, Al1;
      #pragma unroll
      for (int i = 0; i < 8; ++i) {
        float v0 = (i < 4) ? a00[i] : a01[i - 4];
        float v1 = (i < 4) ? a10[i] : a11[i - 4];
        unsigned short h0 = f2bf(v0);
        unsigned short h1 = f2bf(v1);
        Ah0[i] = (short)h0; Al0[i] = (short)f2bf(v0 - bf2f(h0));
        Ah1[i] = (short)h1; Al1[i] = (short)f2bf(v1 - bf2f(h1));
      }

      const int spos = (g * 4 + mt) & (S_LEN - 1);   // wave-uniform seq pos
      const float* ct = cosT + spos * 32;
      const float* st = sinT + spos * 32;

      #pragma unroll
      for (int nt = 0; nt < 4; ++nt) {
        floatx4 acc = {0.f, 0.f, 0.f, 0.f};
        acc = __builtin_amdgcn_mfma_f32_16x16x32_bf16(Ah0, Bf[nt * 4 + 0], acc, 0, 0, 0); // Ah*Bh ks0
        acc = __builtin_amdgcn_mfma_f32_16x16x32_bf16(Ah0, Bf[nt * 4 + 1], acc, 0, 0, 0); // Ah*Bl ks0
        acc = __builtin_amdgcn_mfma_f32_16x16x32_bf16(Al0, Bf[nt * 4 + 0], acc, 0, 0, 0); // Al*Bh ks0
        acc = __builtin_amdgcn_mfma_f32_16x16x32_bf16(Ah1, Bf[nt * 4 + 2], acc, 0, 0, 0); // Ah*Bh ks1
        acc = __builtin_amdgcn_mfma_f32_16x16x32_bf16(Ah1, Bf[nt * 4 + 3], acc, 0, 0, 0); // Ah*Bl ks1
        acc = __builtin_amdgcn_mfma_f32_16x16x32_bf16(Al1, Bf[nt * 4 + 2], acc, 0, 0, 0); // Al*Bh ks1

        // epilogue: logical col = nt*16 + lr, pair d = nt*8 + dq
        const float cv = ct[nt * 8 + dq];
        const float sv = st[nt * 8 + dq];
        const int colout = (lane & 1) ? (32 + nt * 8 + dq) : (nt * 8 + dq);
        float* op = og + (size_t)(mt * 16 + lk * 4) * 64 + colout;
        #pragma unroll
        for (int r = 0; r < 4; ++r) {
          float v = acc[r];
          float p = __shfl_xor(v, 1, 64);
          float o = (lane & 1) ? fmaf(p, sv, v * cv)      // out[32+d] = x1*s + x2*c
                               : fmaf(v, cv, -(p * sv));  // out[d]    = x1*c - x2*s
          op[r * 64] = o;
        }
      }
    }
  }
}

extern "C" void kernel_launch(void* const* d_in, const int* in_sizes, int n_in,
                              void* d_out, int out_size, void* d_ws, size_t ws_size,
                              hipStream_t stream) {
  const float* x           = (const float*)d_in[0];
  const float* thetas      = (const float*)d_in[1];
  const float* theta_scale = (const float*)d_in[2];
  const float* r_matrix    = (const float*)d_in[3];
  const float* inv_freq    = (const float*)d_in[4];
  const int*   r_pairs     = (const int*)d_in[5];

  uint4* Bfrag = (uint4*)d_ws;                  // 16*64*16B = 16KB
  float* cosT  = (float*)d_ws + 4096;           // 512KB
  float* sinT  = cosT + S_LEN * 32;             // 512KB
  float* outp  = (float*)d_out;

  setup_kernel<<<513, 256, 0, stream>>>(thetas, theta_scale, r_matrix, r_pairs,
                                        inv_freq, Bfrag, cosT, sinT);
  rotary_main<<<NWAVE / 4, 256, 0, stream>>>(x, Bfrag, cosT, sinT, outp);
}